// Round 3
// baseline (424.846 us; speedup 1.0000x reference)
//
#include <hip/hip_runtime.h>
#include <math.h>

#define B_ 2
#define N_ 25000
#define E_ 400000
#define D_ 128
#define NRBF 64

#define TPB 256               // 4 waves
#define TILE 64               // edges per tile-step (16/wave)
#define NTILES 25
#define EPB (TILE * NTILES)   // 1600 edges per block
#define WCH (EPB / 4)         // 400 edges per wave
#define GCH (EPB / 16)        // 100 edges per (wave, lane-quad) chunk
#define NBLK (E_ / EPB)       // 250 blocks per batch

typedef short bf8   __attribute__((ext_vector_type(8)));   // MFMA A/B frag (8 bf16)
typedef float f32x4 __attribute__((ext_vector_type(4)));   // MFMA C/D frag
typedef float vf8   __attribute__((ext_vector_type(8)));
typedef float vf16  __attribute__((ext_vector_type(16)));

// f32 -> bf16 bits, round-nearest-even
__device__ __forceinline__ short f2bf(float f) {
    union { float f; unsigned u; } v; v.f = f;
    unsigned r = (v.u + 0x7FFFu + ((v.u >> 16) & 1u)) >> 16;
    return (short)r;
}
// shifted softplus: softplus(x) - ln(2)
__device__ __forceinline__ float ssp(float x) {
    return fmaxf(x, 0.0f) + __logf(1.0f + __expf(-fabsf(x))) - 0.69314718056f;
}

__global__ __launch_bounds__(TPB, 2)
void cfconv_kernel(const float* __restrict__ af,      // [B,N,D]
                   const float* __restrict__ dist,    // [B,E]
                   const int*   __restrict__ idx_j,   // [E]
                   const int*   __restrict__ seg_i,   // [E] (sorted)
                   const float* __restrict__ centers, // [NRBF]
                   const float* __restrict__ gam,     // [NRBF]
                   const float* __restrict__ W1,      // [NRBF,D]
                   const float* __restrict__ b1,      // [D]
                   const float* __restrict__ W2,      // [D,D]
                   const float* __restrict__ b2,      // [D]
                   float* __restrict__ out)           // [B,N,D]
{
    const int t    = threadIdx.x;        // 0..255
    const int lane = t & 63;
    const int w    = t >> 6;             // wave id 0..3
    const int g    = lane >> 4;          // lane quad 0..3
    const int c0   = lane & 15;
    const int b    = blockIdx.y;
    const int e0   = blockIdx.x * EPB;

    // fragment-ready bf16 weights: [c][g][n][j] ; B[k][n], k = c*32+g*8+j
    __shared__ __align__(16) short W1f[2 * 4 * D_ * 8];     // 16 KB (staging for w1r)
    __shared__ __align__(16) short W2f[4 * 4 * D_ * 8];     // 32 KB
    // total 48 KB; NO A2 exchange buffer (h1 transpose is done in-register
    // via operand-swapped GEMM1 + ds_permute lane exchange)

    // ---- prep: weights -> bf16 fragment layout (once per block)
    for (int i = t; i < NRBF * D_; i += TPB) {
        const int k = i >> 7, n = i & 127;
        W1f[(((k >> 5) * 4 + ((k >> 3) & 3)) * D_ + n) * 8 + (k & 7)] = f2bf(W1[i]);
    }
    for (int i = t; i < D_ * D_; i += TPB) {
        const int k = i >> 7, n = i & 127;
        W2f[(((k >> 5) * 4 + ((k >> 3) & 3)) * D_ + n) * 8 + (k & 7)] = f2bf(W2[i]);
    }
    __syncthreads();   // the ONLY block barrier: weights ready

    // ---- W1 fragments: hoist into registers ONCE (16 x bf8 = 64 VGPRs).
    bf8 w1r[2][8];
    #pragma unroll
    for (int c = 0; c < 2; ++c)
        #pragma unroll
        for (int nt = 0; nt < 8; ++nt)
            w1r[c][nt] = *(const bf8*)&W1f[((c * 4 + g) * D_ + nt * 16 + c0) * 8];

    // ---- per-lane constants
    // Swapped GEMM1 output: lane (g,c0) reg r of tile nt = h1[edge=c0][k2=nt*16+g*4+r]
    // -> b1 must be indexed by k2 = nt*16+g*4+r (32 per-lane floats).
    float b1s[32];
    #pragma unroll
    for (int nt = 0; nt < 8; ++nt)
        #pragma unroll
        for (int r = 0; r < 4; ++r)
            b1s[nt * 4 + r] = b1[nt * 16 + g * 4 + r];
    vf8 b2r;
    #pragma unroll
    for (int nt = 0; nt < 8; ++nt) b2r[nt] = b2[nt * 16 + c0];

    // RBF params for exactly the k-slices this lane's rbf fragments need:
    // a0 covers k = g*8+j (j=0..7), a1 covers k = 32+g*8+j
    vf16 gkr, ckr;
    #pragma unroll
    for (int j = 0; j < 8; ++j) {
        gkr[j]     = gam[g * 8 + j];
        gkr[8 + j] = gam[32 + g * 8 + j];
        ckr[j]     = centers[g * 8 + j];
        ckr[8 + j] = centers[32 + g * 8 + j];
    }

    // ds_permute target-lane byte addresses (fixed permutations, loop-invariant):
    // inst1: g -> 2*(g&1) + (g>>1) ; inst2: g -> 2*(1-(g&1)) + (g>>1)
    const int addr1 = ((((g & 1) << 1) | (g >> 1)) * 16 + c0) * 4;
    const int addr2 = (((((g & 1) ^ 1) << 1) | (g >> 1)) * 16 + c0) * 4;

    const float* dist_b = dist + (size_t)b * E_;
    const float* af_b   = af   + (size_t)b * N_ * D_;
    float*       out_b  = out  + (size_t)b * N_ * D_;

    const int ebase = e0 + w * WCH + g * GCH;   // epilogue: this lane-quad's chunk
    // rbf phase: lane (g,c0) supplies edge row m=c0 of its wave's 16-edge tile
    const int eArow = e0 + w * WCH + (c0 >> 2) * GCH + (c0 & 3);

    int cur_seg = -1;
    vf8 pend = (vf8)0.0f;

    for (int s = 0; s < NTILES; ++s) {
        const int et = s * 4;

        // ===== scalar loads for this tile (issued first; coalesced/cached) =====
        const float dd = dist_b[eArow + et];
        int idx[4], sgp[4];
        #pragma unroll
        for (int r = 0; r < 4; ++r) {
            idx[r] = idx_j[ebase + et + r];
            sgp[r] = seg_i[ebase + et + r];
        }

        // ===== gather loads (consumed in epilogue; latency hidden under
        // RBF exp + both GEMM phases) =====
        float rows[4][8];
        #pragma unroll
        for (int r = 0; r < 4; ++r) {
            const float* rowp = af_b + (size_t)idx[r] * D_ + c0;
            #pragma unroll
            for (int nt = 0; nt < 8; ++nt) rows[r][nt] = rowp[nt * 16];
        }

        // ===== Phase A: RBF -> fragments fully in-register =====
        // lane (g,c0) holds (edge index c0, k = c*32+g*8+j) — valid as A OR B frag
        bf8 a0, a1;
        #pragma unroll
        for (int j = 0; j < 8; ++j) {
            const float x0 = dd - ckr[j];
            const float x1 = dd - ckr[8 + j];
            a0[j] = f2bf(__expf(-gkr[j] * x0 * x0));
            a1[j] = f2bf(__expf(-gkr[8 + j] * x1 * x1));
        }

        // ===== Phase B: swapped GEMM1 (h1^T = W1^T @ rbf^T), ssp, and
        // in-register transpose to GEMM2 A-frags via ds_permute =====
        // D1: lane (g,c0) reg r = h1[edge=c0][k2=nt*16+g*4+r].
        // GEMM2 A-frag needs h1[edge=c0][k=c*32+g*8+j]: same c0 column,
        // cross-g exchange. Per (c,pair): 2 staged ds_permute + 2 selects.
        unsigned pw[4][4];
        #pragma unroll
        for (int c = 0; c < 4; ++c) {
            unsigned Pl[2][2];   // packed bf16 pairs for nt=2c (Pl[0]) and 2c+1 (Pl[1])
            #pragma unroll
            for (int h = 0; h < 2; ++h) {
                const int nt = 2 * c + h;
                f32x4 acc = {0.f, 0.f, 0.f, 0.f};
                acc = __builtin_amdgcn_mfma_f32_16x16x32_bf16(w1r[0][nt], a0, acc, 0, 0, 0);
                acc = __builtin_amdgcn_mfma_f32_16x16x32_bf16(w1r[1][nt], a1, acc, 0, 0, 0);
                #pragma unroll
                for (int pr = 0; pr < 2; ++pr) {
                    const float h0 = ssp(acc[2 * pr]     + b1s[nt * 4 + 2 * pr]);
                    const float h1v = ssp(acc[2 * pr + 1] + b1s[nt * 4 + 2 * pr + 1]);
                    Pl[h][pr] = (unsigned)(unsigned short)f2bf(h0)
                              | ((unsigned)(unsigned short)f2bf(h1v) << 16);
                }
            }
            #pragma unroll
            for (int pr = 0; pr < 2; ++pr) {
                // inst1: even-g lanes carry nt=2c, odd-g carry nt=2c+1
                const int s1 = (g & 1) ? (int)Pl[1][pr] : (int)Pl[0][pr];
                // inst2: roles swapped
                const int s2 = (g & 1) ? (int)Pl[0][pr] : (int)Pl[1][pr];
                const int r1 = __builtin_amdgcn_ds_permute(addr1, s1);
                const int r2 = __builtin_amdgcn_ds_permute(addr2, s2);
                // consumers g<2 got their j<4 word from inst1, j>=4 from inst2;
                // consumers g>=2 the opposite.
                pw[c][pr]     = (g < 2) ? (unsigned)r1 : (unsigned)r2;  // j01/j23
                pw[c][2 + pr] = (g < 2) ? (unsigned)r2 : (unsigned)r1;  // j45/j67
            }
        }
        bf8 pc[4];
        #pragma unroll
        for (int c = 0; c < 4; ++c) {
            union { unsigned u[4]; bf8 v; } tu;
            tu.u[0] = pw[c][0]; tu.u[1] = pw[c][1];
            tu.u[2] = pw[c][2]; tu.u[3] = pw[c][3];
            pc[c] = tu.v;
        }

        // ===== Phase C: GEMM2 (filters = h1 @ W2), ssp, gather*filter, scatter =====
        {
            f32x4 facc[8];
            #pragma unroll
            for (int nt = 0; nt < 8; ++nt) {
                const bf8 w0 = *(const bf8*)&W2f[((0 * 4 + g) * D_ + nt * 16 + c0) * 8];
                const bf8 w1v = *(const bf8*)&W2f[((1 * 4 + g) * D_ + nt * 16 + c0) * 8];
                const bf8 w2v = *(const bf8*)&W2f[((2 * 4 + g) * D_ + nt * 16 + c0) * 8];
                const bf8 w3v = *(const bf8*)&W2f[((3 * 4 + g) * D_ + nt * 16 + c0) * 8];
                f32x4 acc = {0.f, 0.f, 0.f, 0.f};
                acc = __builtin_amdgcn_mfma_f32_16x16x32_bf16(pc[0], w0,  acc, 0, 0, 0);
                acc = __builtin_amdgcn_mfma_f32_16x16x32_bf16(pc[1], w1v, acc, 0, 0, 0);
                acc = __builtin_amdgcn_mfma_f32_16x16x32_bf16(pc[2], w2v, acc, 0, 0, 0);
                acc = __builtin_amdgcn_mfma_f32_16x16x32_bf16(pc[3], w3v, acc, 0, 0, 0);
                facc[nt] = acc;
            }
            // epilogue: quad g owns edges ebase + s*4 + r; lane handles cols c0+16*nt
            #pragma unroll
            for (int r = 0; r < 4; ++r) {
                const int sg = sgp[r];
                vf8 msg;
                #pragma unroll
                for (int nt = 0; nt < 8; ++nt) {
                    const float fv = ssp(facc[nt][r] + b2r[nt]);
                    msg[nt] = rows[r][nt] * fv;
                }
                if (sg != cur_seg) {
                    if (cur_seg >= 0) {
                        float* o = out_b + (size_t)cur_seg * D_ + c0;
                        #pragma unroll
                        for (int nt = 0; nt < 8; ++nt) atomicAdd(o + nt * 16, pend[nt]);
                    }
                    cur_seg = sg;
                    pend = msg;
                } else {
                    pend += msg;
                }
            }
        }
    }
    if (cur_seg >= 0) {
        float* o = out_b + (size_t)cur_seg * D_ + c0;
        #pragma unroll
        for (int nt = 0; nt < 8; ++nt) atomicAdd(o + nt * 16, pend[nt]);
    }
}

extern "C" void kernel_launch(void* const* d_in, const int* in_sizes, int n_in,
                              void* d_out, int out_size, void* d_ws, size_t ws_size,
                              hipStream_t stream) {
    const float* af      = (const float*)d_in[0];
    const float* dist    = (const float*)d_in[1];
    const int*   idx_j   = (const int*)d_in[2];
    const int*   seg_i   = (const int*)d_in[3];
    const float* centers = (const float*)d_in[4];
    const float* gam     = (const float*)d_in[5];
    const float* W1      = (const float*)d_in[6];
    const float* b1      = (const float*)d_in[7];
    const float* W2      = (const float*)d_in[8];
    const float* b2      = (const float*)d_in[9];
    float* out = (float*)d_out;

    hipMemsetAsync(out, 0, (size_t)out_size * sizeof(float), stream);

    dim3 grid(NBLK, B_);
    cfconv_kernel<<<grid, TPB, 0, stream>>>(af, dist, idx_j, seg_i,
                                            centers, gam, W1, b1, W2, b2, out);
}